// Round 6
// baseline (782.208 us; speedup 1.0000x reference)
//
#include <hip/hip_runtime.h>
#include <math.h>

#define Bc 32
#define Lc 512
#define Hc 8
#define Ec 64
#define Sc 512

typedef __attribute__((ext_vector_type(8))) _Float16 f16x8;
typedef __attribute__((ext_vector_type(4))) _Float16 f16x4;
typedef __attribute__((ext_vector_type(4))) float    f32x4;

// ---------- helpers ----------
__device__ inline void prior_row(float sg_raw, int lrow, int lane, float* pp) {
    float sg = 1.0f / (1.0f + __expf(-5.0f * sg_raw)) + 1e-5f;
    sg = expm1f(sg * 1.0986122886681098f);
    const float inv = 0.3989422804014327f / sg;
    const float c2  = -0.5f / (sg * sg);
    const int c0 = lane * 8;
    f32x4 o0, o1;
    #pragma unroll
    for (int j = 0; j < 4; ++j) {
        const float d0 = (float)(lrow - (c0 + j));
        const float d1 = (float)(lrow - (c0 + 4 + j));
        o0[j] = inv * __expf(c2 * d0 * d0);
        o1[j] = inv * __expf(c2 * d1 * d1);
    }
    __builtin_nontemporal_store(o0, (f32x4*)(pp + c0));
    __builtin_nontemporal_store(o1, (f32x4*)(pp + c0 + 4));
}

// ---------- combined pack: K fp32 -> fp16 [b][h][s][e]; V fp32 -> fp16 V^T [b][h][e][s]
__global__ __launch_bounds__(256) void pack_kv(const float* __restrict__ K,
                                               const float* __restrict__ V,
                                               _Float16* __restrict__ Kh,
                                               _Float16* __restrict__ Vt) {
    __shared__ float LT[64 * 68];
    const int t = threadIdx.x;
    const int b = blockIdx.z, h = blockIdx.y;
    if (blockIdx.x < 16) {                       // ---- K pack: 32-row slab ----
        const int s0 = blockIdx.x * 32;
        const int e4 = (t & 15) * 4;
        const int sr = t >> 4;                   // 0..15
        #pragma unroll
        for (int i = 0; i < 2; ++i) {
            const int s = s0 + sr + 16 * i;
            const float4 v = *(const float4*)&K[(((size_t)b * Lc + s) * Hc + h) * Ec + e4];
            f16x4 o;
            o[0] = (_Float16)v.x; o[1] = (_Float16)v.y;
            o[2] = (_Float16)v.z; o[3] = (_Float16)v.w;
            *(f16x4*)&Kh[(((size_t)b * Hc + h) * Lc + s) * Ec + e4] = o;
        }
    } else {                                     // ---- V^T pack: 64-row slab ----
        const int s0 = (blockIdx.x - 16) * 64;
        #pragma unroll
        for (int i = 0; i < 16; ++i) {
            const int idx = t + 256 * i;
            const int e = idx & 63, s = idx >> 6;
            LT[e * 68 + s] = V[(((size_t)b * Lc + s0 + s) * Hc + h) * Ec + e];
        }
        __syncthreads();
        #pragma unroll
        for (int i = 0; i < 16; ++i) {
            const int idx = t + 256 * i;
            const int s = idx & 63, e = idx >> 6;
            Vt[((size_t)(b * Hc + h) * Ec + e) * Sc + s0 + s] = (_Float16)LT[e * 68 + s];
        }
    }
}

// ---------- prior tail: covers bh < 32 (the region scratch occupied); runs last ----
__global__ __launch_bounds__(256) void prior_tail(
    const float* __restrict__ sigma, float* __restrict__ prior)
{
    const int wave = threadIdx.x >> 6;
    const int lane = threadIdx.x & 63;
    const int row  = blockIdx.x * 4 + wave;      // (b*H+h)*L + l, bh < 32
    const int l    = row & (Lc - 1);
    const int bh   = row >> 9;
    const int b    = bh >> 3;
    const int h    = bh & (Hc - 1);
    prior_row(sigma[((size_t)b * Lc + l) * Hc + h], l, lane, &prior[(size_t)row * Sc]);
}

// ---------- fused attention + prior (fp16 single-term MFMA) ----------
// 256 thr = 4 waves; block tile = 32 query rows; wave-pairs split the s-range.
// Swapped MFMA (S^T = K.Q^T) with sigma-permuted A rows keeps P^T in exactly
// the PV B-frag layout: acc[nt][r] = P^T[s][l16],
//   s = hs*256 + (nt>>1)*32 + quad*8 + (nt&1)*4 + r.
// Softmax: single (max,sum) LDS exchange (2 barriers total incl. PV exchange).
// Prior fusion: blocks with bh >= 32 write their 32 prior rows in the epilogue
// (scratch occupies exactly the bh<32 slice of the prior region; tail kernel
// covers those after attn).
__global__ __launch_bounds__(256, 4) void attn_mfma(
    const float* __restrict__ Q, const _Float16* __restrict__ Kh,
    const _Float16* __restrict__ Vt, const float* __restrict__ sigma,
    float* __restrict__ outV, float* __restrict__ series, float* __restrict__ prior)
{
    __shared__ float2 pairs[4][16];              // (max, sum) per wave per row
    __shared__ float  ex[2][64][16];             // PV partial exchange (8 KB)

    const int t    = threadIdx.x;
    const int lane = t & 63, wave = t >> 6;
    const int quad = lane >> 4, l16 = lane & 15;
    const int hs   = wave & 1;                   // s-half owned by this wave
    const int rg   = wave >> 1;                  // row group (16 rows)

    // XCD swizzle: all 16 l-tiles of one (b,h) on one XCD (K+V ~100KB L2-hot).
    const int bid = blockIdx.x;                  // 0..4095
    const int xcd = bid & 7;
    const int rr  = bid >> 3;                    // 0..511
    const int xt  = rr & 15;                     // l-tile 0..15 (32 rows each)
    const int bh  = (rr >> 4) * 8 + xcd;         // 0..255
    const int b = bh >> 3, h = bh & 7;
    const int l0 = xt * 32;
    const int l  = l0 + rg * 16 + l16;           // this lane's query row

    const size_t kb = (size_t)bh * Lc * Ec;
    const int sbase = hs * 256;

    // ---- Q B-frags, one-time fp32 -> fp16 convert ----
    f16x8 qf[2];
    {
        const float* qp = &Q[(((size_t)b * Lc + l) * Hc + h) * Ec + quad * 8];
        #pragma unroll
        for (int kt = 0; kt < 2; ++kt) {
            const float4 v0 = *(const float4*)(qp + kt * 32);
            const float4 v1 = *(const float4*)(qp + kt * 32 + 4);
            qf[kt][0] = (_Float16)v0.x; qf[kt][1] = (_Float16)v0.y;
            qf[kt][2] = (_Float16)v0.z; qf[kt][3] = (_Float16)v0.w;
            qf[kt][4] = (_Float16)v1.x; qf[kt][5] = (_Float16)v1.y;
            qf[kt][6] = (_Float16)v1.z; qf[kt][7] = (_Float16)v1.w;
        }
    }

    // ---- QK^T over this wave's 256-col half (single-term fp16) ----
    f32x4 acc[16];
    #pragma unroll
    for (int nt = 0; nt < 16; ++nt) { acc[nt][0]=0.f; acc[nt][1]=0.f; acc[nt][2]=0.f; acc[nt][3]=0.f; }

    const int arow = (l16 >> 2) * 8 + (l16 & 3); // sigma-permuted A-frag row
    #pragma unroll
    for (int nt = 0; nt < 16; ++nt) {
        const int s = sbase + (nt >> 1) * 32 + arow + (nt & 1) * 4;
        const _Float16* kp = &Kh[kb + (size_t)s * Ec + quad * 8];
        #pragma unroll
        for (int kt = 0; kt < 2; ++kt) {
            const f16x8 kf = *(const f16x8*)(kp + kt * 32);
            acc[nt] = __builtin_amdgcn_mfma_f32_16x16x32_f16(kf, qf[kt], acc[nt], 0, 0, 0);
        }
    }

    // ---- softmax: in-lane + quad butterfly; ONE (max,sum) pair exchange ----
    float mx = acc[0][0];
    #pragma unroll
    for (int nt = 0; nt < 16; ++nt) {
        #pragma unroll
        for (int r4 = 0; r4 < 4; ++r4) mx = fmaxf(mx, acc[nt][r4]);
    }
    mx = fmaxf(mx, __shfl_xor(mx, 16));
    mx = fmaxf(mx, __shfl_xor(mx, 32));

    float ssum = 0.f;
    #pragma unroll
    for (int nt = 0; nt < 16; ++nt) {
        #pragma unroll
        for (int r4 = 0; r4 < 4; ++r4) {
            const float e = __expf((acc[nt][r4] - mx) * 0.125f);   // scale = 1/sqrt(64)
            acc[nt][r4] = e; ssum += e;
        }
    }
    ssum += __shfl_xor(ssum, 16);
    ssum += __shfl_xor(ssum, 32);
    if (lane < 16) pairs[wave][lane] = make_float2(mx, ssum);
    __syncthreads();
    const float2 o2 = pairs[wave ^ 1][l16];      // other half's (max, sum)
    const float m   = fmaxf(mx, o2.x);
    const float w0  = __expf((mx   - m) * 0.125f);
    const float w1  = __expf((o2.x - m) * 0.125f);
    const float is  = w0 / (ssum * w0 + o2.y * w1);   // per-half normalizer
    #pragma unroll
    for (int nt = 0; nt < 16; ++nt) {
        acc[nt][0] *= is; acc[nt][1] *= is; acc[nt][2] *= is; acc[nt][3] *= is;
    }

    // ---- fused: series store (exact fp32, nontemporal) + PV partial ----
    f32x4 oaccT[4];
    #pragma unroll
    for (int et = 0; et < 4; ++et) { oaccT[et][0]=0.f; oaccT[et][1]=0.f; oaccT[et][2]=0.f; oaccT[et][3]=0.f; }

    const _Float16* vb = &Vt[(size_t)bh * Ec * Sc];
    float* srow = &series[((size_t)bh * Lc + l) * Sc + sbase];
    #pragma unroll
    for (int t2 = 0; t2 < 8; ++t2) {
        const f32x4 p0 = acc[2 * t2];          // s = sbase + t2*32 + quad*8 + {0..3}
        const f32x4 p1 = acc[2 * t2 + 1];      // s = sbase + t2*32 + quad*8 + {4..7}
        __builtin_nontemporal_store(p0, (f32x4*)&srow[t2 * 32 + quad * 8]);
        __builtin_nontemporal_store(p1, (f32x4*)&srow[t2 * 32 + quad * 8 + 4]);
        f16x8 pb;                               // B-frag P^T, straight from registers
        pb[0] = (_Float16)p0[0]; pb[1] = (_Float16)p0[1];
        pb[2] = (_Float16)p0[2]; pb[3] = (_Float16)p0[3];
        pb[4] = (_Float16)p1[0]; pb[5] = (_Float16)p1[1];
        pb[6] = (_Float16)p1[2]; pb[7] = (_Float16)p1[3];
        #pragma unroll
        for (int et = 0; et < 4; ++et) {
            const f16x8 vf = *(const f16x8*)&vb[(size_t)(et * 16 + l16) * Sc + sbase + t2 * 32 + quad * 8];
            oaccT[et] = __builtin_amdgcn_mfma_f32_16x16x32_f16(vf, pb, oaccT[et], 0, 0, 0);
        }
    }

    // ---- combine PV partials across the wave pair; hs==0 stores outV ----
    if (hs == 1) {
        #pragma unroll
        for (int et = 0; et < 4; ++et)
            *(f32x4*)&ex[rg][lane][et * 4] = oaccT[et];
    }
    __syncthreads();
    if (hs == 0) {
        #pragma unroll
        for (int et = 0; et < 4; ++et) {
            const f32x4 p = *(const f32x4*)&ex[rg][lane][et * 4];
            f32x4 o;
            o[0] = oaccT[et][0] + p[0]; o[1] = oaccT[et][1] + p[1];
            o[2] = oaccT[et][2] + p[2]; o[3] = oaccT[et][3] + p[3];
            // oaccT[et][r] = O^T[e = et*16+quad*4+r][l] -> 16B store
            __builtin_nontemporal_store(o,
                (f32x4*)&outV[(((size_t)b * Lc + l) * Hc + h) * Ec + et * 16 + quad * 4]);
        }
    }

    // ---- fused prior: only for bh >= 32 (scratch lives in bh<32 slice) ----
    if (bh >= 32) {
        #pragma unroll
        for (int r_ = 0; r_ < 8; ++r_) {
            const int lrow = l0 + wave * 8 + r_;
            prior_row(sigma[((size_t)b * Lc + lrow) * Hc + h], lrow, lane,
                      &prior[((size_t)bh * Lc + lrow) * Sc]);
        }
    }
}

extern "C" void kernel_launch(void* const* d_in, const int* in_sizes, int n_in,
                              void* d_out, int out_size, void* d_ws, size_t ws_size,
                              hipStream_t stream) {
    (void)n_in; (void)in_sizes; (void)out_size; (void)d_ws; (void)ws_size;
    const float* Q  = (const float*)d_in[0];
    const float* K  = (const float*)d_in[1];
    const float* Vv = (const float*)d_in[2];
    const float* sg = (const float*)d_in[3];

    float* outV   = (float*)d_out;                               // [B,L,H,E]
    float* series = outV + (size_t)Bc * Lc * Hc * Ec;            // [B,H,L,S]
    float* prior  = series + (size_t)Bc * Hc * Lc * Sc;          // [B,H,L,S]

    // Scratch (exactly 32 MiB = prior rows of bh 0..31) lives at the start of
    // the prior region. attn writes prior for bh>=32; prior_tail covers bh<32
    // afterwards, overwriting the scratch.
    const size_t plane = (size_t)Bc * Hc * Lc * Ec;              // elems per fp16 plane
    _Float16* Kh = (_Float16*)prior;
    _Float16* Vt = Kh + plane;

    pack_kv<<<dim3(24, Hc, Bc), 256, 0, stream>>>(K, Vv, Kh, Vt);
    attn_mfma<<<dim3((Bc * Hc * Lc) / 32, 1, 1), 256, 0, stream>>>(
        Q, Kh, Vt, sg, outV, series, prior);
    prior_tail<<<(32 * Lc) / 4, 256, 0, stream>>>(sg, prior);
}

// Round 7
// 713.686 us; speedup vs baseline: 1.0960x; 1.0960x over previous
//
#include <hip/hip_runtime.h>
#include <math.h>

#define Bc 32
#define Lc 512
#define Hc 8
#define Ec 64
#define Sc 512

typedef __attribute__((ext_vector_type(8))) _Float16 f16x8;
typedef __attribute__((ext_vector_type(4))) _Float16 f16x4;
typedef __attribute__((ext_vector_type(4))) float    f32x4;

// ---------- combined pack: K fp32 -> fp16 [b][h][s][e]; V fp32 -> fp16 V^T [b][h][e][s]
__global__ __launch_bounds__(256) void pack_kv(const float* __restrict__ K,
                                               const float* __restrict__ V,
                                               _Float16* __restrict__ Kh,
                                               _Float16* __restrict__ Vt) {
    __shared__ float LT[64 * 68];
    const int t = threadIdx.x;
    const int b = blockIdx.z, h = blockIdx.y;
    if (blockIdx.x < 16) {                       // ---- K pack: 32-row slab ----
        const int s0 = blockIdx.x * 32;
        const int e4 = (t & 15) * 4;
        const int sr = t >> 4;                   // 0..15
        #pragma unroll
        for (int i = 0; i < 2; ++i) {
            const int s = s0 + sr + 16 * i;
            const float4 v = *(const float4*)&K[(((size_t)b * Lc + s) * Hc + h) * Ec + e4];
            f16x4 o;
            o[0] = (_Float16)v.x; o[1] = (_Float16)v.y;
            o[2] = (_Float16)v.z; o[3] = (_Float16)v.w;
            *(f16x4*)&Kh[(((size_t)b * Hc + h) * Lc + s) * Ec + e4] = o;
        }
    } else {                                     // ---- V^T pack: 64-row slab ----
        const int s0 = (blockIdx.x - 16) * 64;
        #pragma unroll
        for (int i = 0; i < 16; ++i) {
            const int idx = t + 256 * i;
            const int e = idx & 63, s = idx >> 6;
            LT[e * 68 + s] = V[(((size_t)b * Lc + s0 + s) * Hc + h) * Ec + e];
        }
        __syncthreads();
        #pragma unroll
        for (int i = 0; i < 16; ++i) {
            const int idx = t + 256 * i;
            const int s = idx & 63, e = idx >> 6;
            Vt[((size_t)(b * Hc + h) * Ec + e) * Sc + s0 + s] = (_Float16)LT[e * 68 + s];
        }
    }
}

// ---------- prior (standalone, BW-bound near floor; runs last, overwrites scratch) ----------
__global__ __launch_bounds__(256) void prior_kernel(
    const float* __restrict__ sigma, float* __restrict__ prior)
{
    const int wave = threadIdx.x >> 6;
    const int lane = threadIdx.x & 63;
    const int row  = blockIdx.x * 4 + wave;      // (b*H+h)*L + l
    const int l    = row & (Lc - 1);
    const int bh   = row >> 9;
    const int b    = bh >> 3;
    const int h    = bh & (Hc - 1);

    float sg = sigma[((size_t)b * Lc + l) * Hc + h];
    sg = 1.0f / (1.0f + __expf(-5.0f * sg)) + 1e-5f;
    sg = expm1f(sg * 1.0986122886681098f);
    const float inv = 0.3989422804014327f / sg;
    const float c2  = -0.5f / (sg * sg);

    const size_t base = (size_t)row * Sc;
    #pragma unroll
    for (int i = 0; i < 2; ++i) {
        const int s0 = i * 256 + lane * 4;
        const float d0 = (float)(l - (s0 + 0));
        const float d1 = (float)(l - (s0 + 1));
        const float d2 = (float)(l - (s0 + 2));
        const float d3 = (float)(l - (s0 + 3));
        f32x4 o;
        o[0] = inv * __expf(c2 * d0 * d0);
        o[1] = inv * __expf(c2 * d1 * d1);
        o[2] = inv * __expf(c2 * d2 * d2);
        o[3] = inv * __expf(c2 * d3 * d3);
        __builtin_nontemporal_store(o, (f32x4*)&prior[base + s0]);
    }
}

// ---------- fused attention: barrier-free, LDS-free, fp16 single-term MFMA ----------
// 256 thr = 4 INDEPENDENT waves; each wave owns 16 query rows x full 512-col
// s-range. No __syncthreads, no LDS: softmax rows live entirely in-lane
// (128 values) + 2 shuffles across quads. Swapped MFMA (S^T = K.Q^T) with
// sigma-permuted A rows keeps P^T in exactly the PV B-frag layout:
//   acc[nt][r] = P^T[s][l16], s = (nt>>1)*32 + quad*8 + (nt&1)*4 + r.
__global__ __launch_bounds__(256, 2) void attn_mfma(
    const float* __restrict__ Q, const _Float16* __restrict__ Kh,
    const _Float16* __restrict__ Vt,
    float* __restrict__ outV, float* __restrict__ series)
{
    const int t    = threadIdx.x;
    const int lane = t & 63, wave = t >> 6;
    const int quad = lane >> 4, l16 = lane & 15;

    // XCD swizzle: the 8 l-tiles of one (b,h) on one XCD (K+V ~128KB L2-hot).
    const int bid = blockIdx.x;                  // 0..2047
    const int xcd = bid & 7;
    const int rr  = bid >> 3;                    // 0..255
    const int xt  = rr & 7;                      // l-tile 0..7 (64 rows each)
    const int bh  = (rr >> 3) * 8 + xcd;         // 0..255
    const int b = bh >> 3, h = bh & 7;
    const int l  = xt * 64 + wave * 16 + l16;    // this lane's query row

    const size_t kb = (size_t)bh * Lc * Ec;

    // ---- Q B-frags, one-time fp32 -> fp16 convert ----
    f16x8 qf[2];
    {
        const float* qp = &Q[(((size_t)b * Lc + l) * Hc + h) * Ec + quad * 8];
        #pragma unroll
        for (int kt = 0; kt < 2; ++kt) {
            const float4 v0 = *(const float4*)(qp + kt * 32);
            const float4 v1 = *(const float4*)(qp + kt * 32 + 4);
            qf[kt][0] = (_Float16)v0.x; qf[kt][1] = (_Float16)v0.y;
            qf[kt][2] = (_Float16)v0.z; qf[kt][3] = (_Float16)v0.w;
            qf[kt][4] = (_Float16)v1.x; qf[kt][5] = (_Float16)v1.y;
            qf[kt][6] = (_Float16)v1.z; qf[kt][7] = (_Float16)v1.w;
        }
    }

    // ---- QK^T over full 512-col s-range (single-term fp16) ----
    f32x4 acc[32];
    #pragma unroll
    for (int nt = 0; nt < 32; ++nt) { acc[nt][0]=0.f; acc[nt][1]=0.f; acc[nt][2]=0.f; acc[nt][3]=0.f; }

    const int arow = (l16 >> 2) * 8 + (l16 & 3); // sigma-permuted A-frag row
    #pragma unroll
    for (int nt = 0; nt < 32; ++nt) {
        const int s = (nt >> 1) * 32 + arow + (nt & 1) * 4;
        const _Float16* kp = &Kh[kb + (size_t)s * Ec + quad * 8];
        #pragma unroll
        for (int kt = 0; kt < 2; ++kt) {
            const f16x8 kf = *(const f16x8*)(kp + kt * 32);
            acc[nt] = __builtin_amdgcn_mfma_f32_16x16x32_f16(kf, qf[kt], acc[nt], 0, 0, 0);
        }
    }

    // ---- softmax fully in-lane: 128 values + quad butterfly ----
    float mx = acc[0][0];
    #pragma unroll
    for (int nt = 0; nt < 32; ++nt) {
        #pragma unroll
        for (int r4 = 0; r4 < 4; ++r4) mx = fmaxf(mx, acc[nt][r4]);
    }
    mx = fmaxf(mx, __shfl_xor(mx, 16));
    mx = fmaxf(mx, __shfl_xor(mx, 32));
    float ssum = 0.f;
    #pragma unroll
    for (int nt = 0; nt < 32; ++nt) {
        #pragma unroll
        for (int r4 = 0; r4 < 4; ++r4) {
            const float e = __expf((acc[nt][r4] - mx) * 0.125f);   // scale = 1/sqrt(64)
            acc[nt][r4] = e; ssum += e;
        }
    }
    ssum += __shfl_xor(ssum, 16);
    ssum += __shfl_xor(ssum, 32);
    const float is = 1.f / ssum;
    #pragma unroll
    for (int nt = 0; nt < 32; ++nt) {
        acc[nt][0] *= is; acc[nt][1] *= is; acc[nt][2] *= is; acc[nt][3] *= is;
    }

    // ---- fused: series store (exact fp32, nontemporal) + PV ----
    f32x4 oaccT[4];
    #pragma unroll
    for (int et = 0; et < 4; ++et) { oaccT[et][0]=0.f; oaccT[et][1]=0.f; oaccT[et][2]=0.f; oaccT[et][3]=0.f; }

    const _Float16* vb = &Vt[(size_t)bh * Ec * Sc];
    float* srow = &series[((size_t)bh * Lc + l) * Sc];
    #pragma unroll
    for (int t2 = 0; t2 < 16; ++t2) {
        const f32x4 p0 = acc[2 * t2];          // s = t2*32 + quad*8 + {0..3}
        const f32x4 p1 = acc[2 * t2 + 1];      // s = t2*32 + quad*8 + {4..7}
        __builtin_nontemporal_store(p0, (f32x4*)&srow[t2 * 32 + quad * 8]);
        __builtin_nontemporal_store(p1, (f32x4*)&srow[t2 * 32 + quad * 8 + 4]);
        f16x8 pb;                               // B-frag P^T, straight from registers
        pb[0] = (_Float16)p0[0]; pb[1] = (_Float16)p0[1];
        pb[2] = (_Float16)p0[2]; pb[3] = (_Float16)p0[3];
        pb[4] = (_Float16)p1[0]; pb[5] = (_Float16)p1[1];
        pb[6] = (_Float16)p1[2]; pb[7] = (_Float16)p1[3];
        #pragma unroll
        for (int et = 0; et < 4; ++et) {
            const f16x8 vf = *(const f16x8*)&vb[(size_t)(et * 16 + l16) * Sc + t2 * 32 + quad * 8];
            oaccT[et] = __builtin_amdgcn_mfma_f32_16x16x32_f16(vf, pb, oaccT[et], 0, 0, 0);
        }
    }

    // ---- epilogue: oaccT[et][r] = O^T[e = et*16+quad*4+r][l] -> float4 stores ----
    #pragma unroll
    for (int et = 0; et < 4; ++et) {
        __builtin_nontemporal_store(oaccT[et],
            (f32x4*)&outV[(((size_t)b * Lc + l) * Hc + h) * Ec + et * 16 + quad * 4]);
    }
}

extern "C" void kernel_launch(void* const* d_in, const int* in_sizes, int n_in,
                              void* d_out, int out_size, void* d_ws, size_t ws_size,
                              hipStream_t stream) {
    (void)n_in; (void)in_sizes; (void)out_size; (void)d_ws; (void)ws_size;
    const float* Q  = (const float*)d_in[0];
    const float* K  = (const float*)d_in[1];
    const float* Vv = (const float*)d_in[2];
    const float* sg = (const float*)d_in[3];

    float* outV   = (float*)d_out;                               // [B,L,H,E]
    float* series = outV + (size_t)Bc * Lc * Hc * Ec;            // [B,H,L,S]
    float* prior  = series + (size_t)Bc * Hc * Lc * Sc;          // [B,H,L,S]

    // Scratch (33.6 MB) lives at the start of the prior region (268 MB);
    // prior_kernel runs last and overwrites it. (Placement proven R0-R2, R5.)
    const size_t plane = (size_t)Bc * Hc * Lc * Ec;              // elems per fp16 plane
    _Float16* Kh = (_Float16*)prior;
    _Float16* Vt = Kh + plane;

    pack_kv<<<dim3(24, Hc, Bc), 256, 0, stream>>>(K, Vv, Kh, Vt);
    attn_mfma<<<dim3((Bc * Hc * Lc) / 64, 1, 1), 256, 0, stream>>>(
        Q, Kh, Vt, outV, series);
    prior_kernel<<<(Bc * Hc * Lc) / 4, 256, 0, stream>>>(sg, prior);
}